// Round 11
// baseline (44.025 us; speedup 1.0000x reference)
//
#include <hip/hip_runtime.h>
#include <hip/hip_fp16.h>

typedef int          __attribute__((ext_vector_type(4))) i32x4;
typedef float        __attribute__((ext_vector_type(4))) f32x4;
typedef unsigned int __attribute__((ext_vector_type(2))) u32x2;

constexpr int B_ = 8;
constexpr int N_ = 8192;
constexpr int K_ = 100;
constexpr int PER_BATCH = N_ * K_;                 // 819200 elements
constexpr int QUADS_PER_BATCH = PER_BATCH / 4;     // 204800 quads
constexpr int THREADS = 1024;                      // 16 waves
constexpr int BLOCKS_PER_BATCH = 32;
constexpr int GRID = B_ * BLOCKS_PER_BATCH;        // 256 blocks -> 1/CU
constexpr int QUADS_PER_BLOCK = QUADS_PER_BATCH / BLOCKS_PER_BATCH; // 6400
constexpr int TILE = 2048;                         // quads per full tile (2/thread)
constexpr int TAILQ = QUADS_PER_BLOCK - 3 * TILE;  // 256

constexpr float RMIN2 = 0.01f;   // 0.1^2
constexpr float RMAX2 = 4.0f;    // 2.0^2

__device__ __forceinline__ u32x2 pack_pos(float x, float y, float z) {
    const unsigned hx = __half_as_ushort(__float2half_rn(x));
    const unsigned hy = __half_as_ushort(__float2half_rn(y));
    const unsigned hz = __half_as_ushort(__float2half_rn(z));
    u32x2 r; r.x = hx | (hy << 16); r.y = hz;
    return r;
}

__global__ __launch_bounds__(THREADS, 1)
void repulsive_prior_kernel(const float* __restrict__ positions,  // [B,N,3]
                            const float* __restrict__ cell,       // [B,3,3]
                            const float* __restrict__ offsets,    // [B,N,K,3]
                            const int*   __restrict__ neighbors,  // [B,N,K]
                            const int*   __restrict__ mask,       // [B,N,K]
                            float* __restrict__ out)              // [B]
{
    __shared__ u32x2 spos[N_];            // 64 KB: f16 xyz -> 1 ds_read_b64/gather
    __shared__ i32x4 nbbuf[2][TILE];      // 2 x 32 KB: DMA'd neighbor stream
    __shared__ float wsum[THREADS / 64];

    const int bid   = blockIdx.x;
    const int b     = bid & 7;             // XCD-affine batch mapping
    const int chunk = bid >> 3;            // 0..31
    const int t     = (int)threadIdx.x;
    const int wid   = t >> 6;
    const int lane  = t & 63;

    const float* __restrict__ pos_b = positions + (size_t)b * N_ * 3;
    const float* __restrict__ off_b = offsets   + (size_t)b * PER_BATCH * 3;
    const int*   __restrict__ nb_b  = neighbors + (size_t)b * PER_BATCH;
    const int*   __restrict__ mk_b  = mask      + (size_t)b * PER_BATCH;

    const int qbase = chunk * QUADS_PER_BLOCK;

    // ---- DMA a tile of neighbor quads into nbbuf[bufidx] (1KB chunks/wave) ----
    auto dma_nb = [&](int bufidx, int q0, int nq) {
        const int nchunks = nq >> 6;             // 64 quads (1 KB) per chunk
        for (int c = wid; c < nchunks; c += THREADS / 64) {
            const int* src = nb_b + 4 * (size_t)(q0 + c * 64) + lane * 4;
            __builtin_amdgcn_global_load_lds(
                (const __attribute__((address_space(1))) unsigned int*)src,
                (__attribute__((address_space(3))) unsigned int*)&nbbuf[bufidx][c * 64],
                16, 0, 0);
        }
    };

    // ---- VGPR stream prefetch (mask + offsets) ----
    struct SQ { i32x4 mk; f32x4 oa, ob, oc; };
    auto loadS = [&](int q) {
        SQ s;
        s.mk = *(const i32x4*)(mk_b  + 4 * (size_t)q);
        s.oa = *(const f32x4*)(off_b + 12 * (size_t)q);
        s.ob = *(const f32x4*)(off_b + 12 * (size_t)q + 4);
        s.oc = *(const f32x4*)(off_b + 12 * (size_t)q + 8);
        return s;
    };

    // ---- prologue: issue tile0 DMA + tile0 VGPR streams, then stage spos ----
    dma_nb(0, qbase, TILE);
    SQ a0 = loadS(qbase + t);
    SQ a1 = loadS(qbase + 1024 + t);

    #pragma unroll
    for (int g0 = 0; g0 < 2; ++g0) {
        const int g = g0 * THREADS + t;            // 0..2047 (4 rows each)
        const f32x4 v0 = *(const f32x4*)(pos_b + 12 * (size_t)g);
        const f32x4 v1 = *(const f32x4*)(pos_b + 12 * (size_t)g + 4);
        const f32x4 v2 = *(const f32x4*)(pos_b + 12 * (size_t)g + 8);
        spos[4 * g + 0] = pack_pos(v0.x, v0.y, v0.z);
        spos[4 * g + 1] = pack_pos(v0.w, v1.x, v1.y);
        spos[4 * g + 2] = pack_pos(v1.z, v1.w, v2.x);
        spos[4 * g + 3] = pack_pos(v2.y, v2.z, v2.w);
    }
    __syncthreads();   // drains vmcnt(0)+lgkmcnt(0): tile0 DMA + spos ready

    const float* cb = cell + b * 9;
    const float c00 = cb[0], c01 = cb[1], c02 = cb[2];
    const float c10 = cb[3], c11 = cb[4], c12 = cb[5];
    const float c20 = cb[6], c21 = cb[7], c22 = cb[8];

    auto ldpos = [&](int row, float& x, float& y, float& z) {
        const u32x2 v = spos[row];
        x = __half2float(__ushort_as_half((unsigned short)(v.x & 0xffffu)));
        y = __half2float(__ushort_as_half((unsigned short)(v.x >> 16)));
        z = __half2float(__ushort_as_half((unsigned short)(v.y & 0xffffu)));
    };

    float acc = 0.0f;
    auto computeq = [&](const SQ& Q, const i32x4 nb, int q) {
        const int n = q / 25;                 // 25 quads per row (K=100)
        float pix, piy, piz;
        ldpos(n, pix, piy, piz);
        auto elem = [&](int m, int j, float o0, float o1, float o2) {
            float pjx, pjy, pjz;
            ldpos(j, pjx, pjy, pjz);
            const float vx = pjx + o0 * c00 + o1 * c10 + o2 * c20 - pix;
            const float vy = pjy + o0 * c01 + o1 * c11 + o2 * c21 - piy;
            const float vz = pjz + o0 * c02 + o1 * c12 + o2 * c22 - piz;
            const float sq = vx * vx + vy * vy + vz * vz;
            const bool keep = (m > 0) & (sq >= RMIN2) & (sq <= RMAX2);
            acc += keep ? (1.0f / sq) : 0.0f;
        };
        elem(Q.mk.x, nb.x, Q.oa.x, Q.oa.y, Q.oa.z);
        elem(Q.mk.y, nb.y, Q.oa.w, Q.ob.x, Q.ob.y);
        elem(Q.mk.z, nb.z, Q.ob.z, Q.ob.w, Q.oc.x);
        elem(Q.mk.w, nb.w, Q.oc.y, Q.oc.z, Q.oc.w);
    };

    // ---- iter 0: prefetch tile1 -> buf1; compute tile0 from buf0 ----
    dma_nb(1, qbase + TILE, TILE);
    SQ b0 = loadS(qbase + TILE + t);
    SQ b1 = loadS(qbase + TILE + 1024 + t);
    __builtin_amdgcn_sched_barrier(0);     // pin prefetch issue above compute
    computeq(a0, nbbuf[0][t],        qbase + t);
    computeq(a1, nbbuf[0][1024 + t], qbase + 1024 + t);
    __syncthreads();                        // tile1 DMA complete + visible

    // ---- iter 1: prefetch tile2 -> buf0; compute tile1 from buf1 ----
    dma_nb(0, qbase + 2 * TILE, TILE);
    SQ e0 = loadS(qbase + 2 * TILE + t);
    SQ e1 = loadS(qbase + 2 * TILE + 1024 + t);
    __builtin_amdgcn_sched_barrier(0);
    computeq(b0, nbbuf[1][t],        qbase + TILE + t);
    computeq(b1, nbbuf[1][1024 + t], qbase + TILE + 1024 + t);
    __syncthreads();

    // ---- iter 2: prefetch tail -> buf1; compute tile2 from buf0 ----
    dma_nb(1, qbase + 3 * TILE, TAILQ);
    SQ d0;
    if (t < TAILQ) d0 = loadS(qbase + 3 * TILE + t);
    __builtin_amdgcn_sched_barrier(0);
    computeq(e0, nbbuf[0][t],        qbase + 2 * TILE + t);
    computeq(e1, nbbuf[0][1024 + t], qbase + 2 * TILE + 1024 + t);
    __syncthreads();

    // ---- iter 3: compute tail from buf1 ----
    if (t < TAILQ)
        computeq(d0, nbbuf[1][t], qbase + 3 * TILE + t);

    // ---- reduce ----
    #pragma unroll
    for (int off = 32; off > 0; off >>= 1)
        acc += __shfl_down(acc, off, 64);

    if (lane == 0) wsum[wid] = acc;
    __syncthreads();
    if (t == 0) {
        float s = 0.0f;
        #pragma unroll
        for (int w = 0; w < THREADS / 64; ++w) s += wsum[w];
        atomicAdd(&out[b], 0.5f * s);
    }
}

extern "C" void kernel_launch(void* const* d_in, const int* in_sizes, int n_in,
                              void* d_out, int out_size, void* d_ws, size_t ws_size,
                              hipStream_t stream) {
    const float* positions = (const float*)d_in[0];
    const float* cell      = (const float*)d_in[1];
    const float* offsets   = (const float*)d_in[2];
    const int*   neighbors = (const int*)d_in[3];
    const int*   mask      = (const int*)d_in[4];
    float* out = (float*)d_out;

    (void)hipMemsetAsync(out, 0, out_size * sizeof(float), stream);

    repulsive_prior_kernel<<<GRID, THREADS, 0, stream>>>(
        positions, cell, offsets, neighbors, mask, out);
}

// Round 12
// 33.668 us; speedup vs baseline: 1.3076x; 1.3076x over previous
//
#include <hip/hip_runtime.h>
#include <hip/hip_fp16.h>

typedef int          __attribute__((ext_vector_type(2))) i32x2;
typedef float        __attribute__((ext_vector_type(2))) f32x2;
typedef float        __attribute__((ext_vector_type(4))) f32x4;
typedef unsigned int __attribute__((ext_vector_type(2))) u32x2;

constexpr int B_ = 8;
constexpr int N_ = 8192;
constexpr int K_ = 100;
constexpr int PER_BATCH = N_ * K_;                 // 819200 elements per batch
constexpr int THREADS = 1024;                      // 16 waves
constexpr int NWAVES = THREADS / 64;
constexpr int BLOCKS_PER_BATCH = 32;
constexpr int GRID = B_ * BLOCKS_PER_BATCH;        // 256 blocks -> 1/CU
constexpr int ELEMS_PER_BLOCK = PER_BATCH / BLOCKS_PER_BATCH;   // 25600
constexpr int TILE_E = 2048;                       // elements per full tile
constexpr int NFULL = 12;                          // 12*2048 = 24576
constexpr int TAIL_E = ELEMS_PER_BLOCK - NFULL * TILE_E;        // 1024
constexpr int NTILES = NFULL + 1;                  // 13

constexpr float RMIN2 = 0.01f;   // 0.1^2
constexpr float RMAX2 = 4.0f;    // 2.0^2

__device__ __forceinline__ u32x2 pack_pos(float x, float y, float z) {
    const unsigned hx = __half_as_ushort(__float2half_rn(x));
    const unsigned hy = __half_as_ushort(__float2half_rn(y));
    const unsigned hz = __half_as_ushort(__float2half_rn(z));
    u32x2 r; r.x = hx | (hy << 16); r.y = hz;
    return r;
}

struct StreamBuf {              // one tile of streams, mirrored from global
    int   nb[TILE_E];           // 8 KB
    int   mk[TILE_E];           // 8 KB
    float off[3 * TILE_E];      // 24 KB
};                              // 40 KB

__global__ __launch_bounds__(THREADS, 1)
void repulsive_prior_kernel(const float* __restrict__ positions,  // [B,N,3]
                            const float* __restrict__ cell,       // [B,3,3]
                            const float* __restrict__ offsets,    // [B,N,K,3]
                            const int*   __restrict__ neighbors,  // [B,N,K]
                            const int*   __restrict__ mask,       // [B,N,K]
                            float* __restrict__ out)              // [B]
{
    __shared__ u32x2 spos[N_];          // 64 KB f16 positions
    __shared__ StreamBuf sbuf[2];       // 80 KB double-buffered streams
    __shared__ float wsum[NWAVES];

    const int bid   = blockIdx.x;
    const int b     = bid & 7;           // XCD-affine batch mapping
    const int chunk = bid >> 3;          // 0..31
    const int t     = (int)threadIdx.x;
    const int wid   = t >> 6;
    const int lane  = t & 63;

    const float* __restrict__ pos_b = positions + (size_t)b * N_ * 3;
    const float* __restrict__ off_b = offsets   + (size_t)b * PER_BATCH * 3;
    const int*   __restrict__ nb_b  = neighbors + (size_t)b * PER_BATCH;
    const int*   __restrict__ mk_b  = mask      + (size_t)b * PER_BATCH;

    const int Ebase0 = chunk * ELEMS_PER_BLOCK;   // element base for this block

    // ---- DMA one stream tile into sbuf[bi]; no VGPR destinations ----
    auto dma = [&](int bi, int Eb, int ne) {
        StreamBuf* sb = &sbuf[bi];
        const int nbc   = ne >> 8;                // 1KB chunks per int array
        const int total = 5 * nbc;                // nb + mk + 3x off
        for (int c = wid; c < total; c += NWAVES) {
            const int* gsrc;
            int* ldst;
            if (c < nbc) {
                gsrc = nb_b + Eb + (c << 8);
                ldst = &sb->nb[c << 8];
            } else if (c < 2 * nbc) {
                gsrc = mk_b + Eb + ((c - nbc) << 8);
                ldst = &sb->mk[(c - nbc) << 8];
            } else {
                gsrc = (const int*)(off_b + 3 * (size_t)Eb) + ((c - 2 * nbc) << 8);
                ldst = (int*)&sb->off[(c - 2 * nbc) << 8];
            }
            __builtin_amdgcn_global_load_lds(
                (const __attribute__((address_space(1))) unsigned int*)(gsrc + lane * 4),
                (__attribute__((address_space(3))) unsigned int*)ldst,
                16, 0, 0);
        }
    };

    // ---- prologue: DMA tile0 while staging positions ----
    dma(0, Ebase0, TILE_E);

    #pragma unroll
    for (int g0 = 0; g0 < 2; ++g0) {
        const int g = g0 * THREADS + t;            // 0..2047 (4 rows each)
        const f32x4 v0 = *(const f32x4*)(pos_b + 12 * (size_t)g);
        const f32x4 v1 = *(const f32x4*)(pos_b + 12 * (size_t)g + 4);
        const f32x4 v2 = *(const f32x4*)(pos_b + 12 * (size_t)g + 8);
        spos[4 * g + 0] = pack_pos(v0.x, v0.y, v0.z);
        spos[4 * g + 1] = pack_pos(v0.w, v1.x, v1.y);
        spos[4 * g + 2] = pack_pos(v1.z, v1.w, v2.x);
        spos[4 * g + 3] = pack_pos(v2.y, v2.z, v2.w);
    }
    __syncthreads();     // tile0 DMA + spos complete

    const float* cb = cell + b * 9;
    const float c00 = cb[0], c01 = cb[1], c02 = cb[2];
    const float c10 = cb[3], c11 = cb[4], c12 = cb[5];
    const float c20 = cb[6], c21 = cb[7], c22 = cb[8];

    auto ldpos = [&](int row, float& x, float& y, float& z) {
        const u32x2 v = spos[row];
        x = __half2float(__ushort_as_half((unsigned short)(v.x & 0xffffu)));
        y = __half2float(__ushort_as_half((unsigned short)(v.x >> 16)));
        z = __half2float(__ushort_as_half((unsigned short)(v.y & 0xffffu)));
    };

    float acc = 0.0f;
    auto elem = [&](int Ei, int m, int j, float o0, float o1, float o2) {
        const int n = Ei / 100;
        float pix, piy, piz, pjx, pjy, pjz;
        ldpos(n, pix, piy, piz);
        ldpos(j, pjx, pjy, pjz);
        const float vx = pjx + o0 * c00 + o1 * c10 + o2 * c20 - pix;
        const float vy = pjy + o0 * c01 + o1 * c11 + o2 * c21 - piy;
        const float vz = pjz + o0 * c02 + o1 * c12 + o2 * c22 - piz;
        const float sq = vx * vx + vy * vy + vz * vz;
        const bool keep = (m > 0) & (sq >= RMIN2) & (sq <= RMAX2);
        acc += keep ? (1.0f / sq) : 0.0f;
    };

    // ---- main loop: prefetch tile k+1 via DMA, compute tile k from LDS ----
    #pragma unroll 1
    for (int k = 0; k < NTILES; ++k) {
        if (k < NTILES - 1)
            dma((k + 1) & 1, Ebase0 + (k + 1) * TILE_E,
                (k + 1 == NFULL) ? TAIL_E : TILE_E);

        StreamBuf* sb = &sbuf[k & 1];
        const int ne = (k == NFULL) ? TAIL_E : TILE_E;
        const int e0 = 2 * t;
        if (e0 < ne) {
            const i32x2 nb2 = *(const i32x2*)&sb->nb[e0];
            const i32x2 mk2 = *(const i32x2*)&sb->mk[e0];
            const f32x2 o01 = *(const f32x2*)&sb->off[3 * e0];
            const f32x2 o23 = *(const f32x2*)&sb->off[3 * e0 + 2];
            const f32x2 o45 = *(const f32x2*)&sb->off[3 * e0 + 4];
            const int Ei = Ebase0 + k * TILE_E + e0;
            elem(Ei,     mk2.x, nb2.x, o01.x, o01.y, o23.x);
            elem(Ei + 1, mk2.y, nb2.y, o23.y, o45.x, o45.y);
        }
        __syncthreads();   // next tile's DMA drained + sbuf[k&1] free
    }

    // ---- reduce ----
    #pragma unroll
    for (int off = 32; off > 0; off >>= 1)
        acc += __shfl_down(acc, off, 64);

    if (lane == 0) wsum[wid] = acc;
    __syncthreads();
    if (t == 0) {
        float s = 0.0f;
        #pragma unroll
        for (int w = 0; w < NWAVES; ++w) s += wsum[w];
        atomicAdd(&out[b], 0.5f * s);
    }
}

extern "C" void kernel_launch(void* const* d_in, const int* in_sizes, int n_in,
                              void* d_out, int out_size, void* d_ws, size_t ws_size,
                              hipStream_t stream) {
    const float* positions = (const float*)d_in[0];
    const float* cell      = (const float*)d_in[1];
    const float* offsets   = (const float*)d_in[2];
    const int*   neighbors = (const int*)d_in[3];
    const int*   mask      = (const int*)d_in[4];
    float* out = (float*)d_out;

    (void)hipMemsetAsync(out, 0, out_size * sizeof(float), stream);

    repulsive_prior_kernel<<<GRID, THREADS, 0, stream>>>(
        positions, cell, offsets, neighbors, mask, out);
}

// Round 13
// 31.340 us; speedup vs baseline: 1.4048x; 1.0743x over previous
//
#include <hip/hip_runtime.h>
#include <hip/hip_fp16.h>

typedef float        __attribute__((ext_vector_type(4))) f32x4;
typedef unsigned int __attribute__((ext_vector_type(2))) u32x2;

constexpr int B_ = 8;
constexpr int N_ = 8192;
constexpr int K_ = 100;
constexpr int PER_BATCH = N_ * K_;                 // 819200 elements per batch
constexpr int THREADS = 1024;                      // 16 waves
constexpr int NWAVES = THREADS / 64;
constexpr int BLOCKS_PER_BATCH = 32;
constexpr int GRID = B_ * BLOCKS_PER_BATCH;        // 256 blocks -> 1/CU
constexpr int ELEMS_PER_BLOCK = PER_BATCH / BLOCKS_PER_BATCH;   // 25600
constexpr int TILE_E = 1024;                       // elements per tile (1/thread)
constexpr int NTILES = ELEMS_PER_BLOCK / TILE_E;   // 25, exact — no tail
constexpr int NBUF = 4;                            // 3 tiles in flight + 1 compute

constexpr float RMIN2 = 0.01f;   // 0.1^2
constexpr float RMAX2 = 4.0f;    // 2.0^2

__device__ __forceinline__ u32x2 pack_pos(float x, float y, float z) {
    const unsigned hx = __half_as_ushort(__float2half_rn(x));
    const unsigned hy = __half_as_ushort(__float2half_rn(y));
    const unsigned hz = __half_as_ushort(__float2half_rn(z));
    u32x2 r; r.x = hx | (hy << 16); r.y = hz;
    return r;
}

struct StreamBuf {              // one 1024-elem tile of streams (20 KB)
    int   nb[TILE_E];           // 4 KB = chunks 0..3
    int   mk[TILE_E];           // 4 KB = chunks 4..7
    float off[3 * TILE_E];      // 12 KB = chunks 8..19
};

__global__ __launch_bounds__(THREADS, 1)
void repulsive_prior_kernel(const float* __restrict__ positions,  // [B,N,3]
                            const float* __restrict__ cell,       // [B,3,3]
                            const float* __restrict__ offsets,    // [B,N,K,3]
                            const int*   __restrict__ neighbors,  // [B,N,K]
                            const int*   __restrict__ mask,       // [B,N,K]
                            float* __restrict__ out)              // [B]
{
    __shared__ u32x2 spos[N_];          // 64 KB f16 positions
    __shared__ StreamBuf sbuf[NBUF];    // 80 KB quad-buffered streams
    __shared__ float wsum[NWAVES];

    const int bid   = blockIdx.x;
    const int b     = bid & 7;           // XCD-affine batch mapping
    const int chunk = bid >> 3;          // 0..31
    const int t     = (int)threadIdx.x;
    const int wid   = t >> 6;
    const int lane  = t & 63;

    const float* __restrict__ pos_b = positions + (size_t)b * N_ * 3;
    const float* __restrict__ off_b = offsets   + (size_t)b * PER_BATCH * 3;
    const int*   __restrict__ nb_b  = neighbors + (size_t)b * PER_BATCH;
    const int*   __restrict__ mk_b  = mask      + (size_t)b * PER_BATCH;

    const int Ebase0 = chunk * ELEMS_PER_BLOCK;

    // ---- DMA one tile: waves 0..9 each move 2 fixed 1KB chunks (20 total) ----
    auto dma_tile = [&](int bi, int tileIdx) {
        if (wid < 10) {
            StreamBuf* sb = &sbuf[bi];
            const int Eb = Ebase0 + tileIdx * TILE_E;
            #pragma unroll
            for (int s = 0; s < 2; ++s) {
                const int c = 2 * wid + s;           // 0..19, wave-uniform
                const int* gsrc;
                int* ldst;
                if (c < 4)      { gsrc = nb_b + Eb + (c << 8);
                                  ldst = &sb->nb[c << 8]; }
                else if (c < 8) { gsrc = mk_b + Eb + ((c - 4) << 8);
                                  ldst = &sb->mk[(c - 4) << 8]; }
                else            { gsrc = (const int*)(off_b + 3 * (size_t)Eb) + ((c - 8) << 8);
                                  ldst = (int*)&sb->off[(c - 8) << 8]; }
                __builtin_amdgcn_global_load_lds(
                    (const __attribute__((address_space(1))) unsigned int*)(gsrc + lane * 4),
                    (__attribute__((address_space(3))) unsigned int*)ldst,
                    16, 0, 0);
            }
        }
    };

    // ---- prologue: tiles 0..2 in flight while staging positions ----
    dma_tile(0, 0);
    dma_tile(1, 1);
    dma_tile(2, 2);

    #pragma unroll
    for (int g0 = 0; g0 < 2; ++g0) {
        const int g = g0 * THREADS + t;            // 0..2047 (4 rows each)
        const f32x4 v0 = *(const f32x4*)(pos_b + 12 * (size_t)g);
        const f32x4 v1 = *(const f32x4*)(pos_b + 12 * (size_t)g + 4);
        const f32x4 v2 = *(const f32x4*)(pos_b + 12 * (size_t)g + 8);
        spos[4 * g + 0] = pack_pos(v0.x, v0.y, v0.z);
        spos[4 * g + 1] = pack_pos(v0.w, v1.x, v1.y);
        spos[4 * g + 2] = pack_pos(v1.z, v1.w, v2.x);
        spos[4 * g + 3] = pack_pos(v2.y, v2.z, v2.w);
    }
    __syncthreads();     // drains prologue (tiles 0-2 + spos) once; loop refills

    const float* cb = cell + b * 9;
    const float c00 = cb[0], c01 = cb[1], c02 = cb[2];
    const float c10 = cb[3], c11 = cb[4], c12 = cb[5];
    const float c20 = cb[6], c21 = cb[7], c22 = cb[8];

    auto ldpos = [&](int row, float& x, float& y, float& z) {
        const u32x2 v = spos[row];
        x = __half2float(__ushort_as_half((unsigned short)(v.x & 0xffffu)));
        y = __half2float(__ushort_as_half((unsigned short)(v.x >> 16)));
        z = __half2float(__ushort_as_half((unsigned short)(v.y & 0xffffu)));
    };

    float acc = 0.0f;

    // ---- main loop: counted-vmcnt pipeline, 3 tiles in flight ----
    #pragma unroll 1
    for (int k = 0; k < NTILES; ++k) {
        if (k > 0) {
            // own 2 future tiles (2 chunks each) may stay outstanding
            asm volatile("s_waitcnt vmcnt(4)" ::: "memory");
            __builtin_amdgcn_sched_barrier(0);
            __builtin_amdgcn_s_barrier();      // tile k fully in LDS for all waves
        }
        if (k + 3 < NTILES)
            dma_tile((k + 3) & 3, k + 3);      // buf freed by barrier above
        __builtin_amdgcn_sched_barrier(0);     // pin DMA issue before compute

        const StreamBuf* sb = &sbuf[k & 3];
        const int j  = sb->nb[t];
        const int m  = sb->mk[t];
        const float o0 = sb->off[3 * t + 0];
        const float o1 = sb->off[3 * t + 1];
        const float o2 = sb->off[3 * t + 2];
        const int Ei = Ebase0 + k * TILE_E + t;
        const int n  = Ei / 100;

        float pix, piy, piz, pjx, pjy, pjz;
        ldpos(n, pix, piy, piz);
        ldpos(j, pjx, pjy, pjz);
        const float vx = pjx + o0 * c00 + o1 * c10 + o2 * c20 - pix;
        const float vy = pjy + o0 * c01 + o1 * c11 + o2 * c21 - piy;
        const float vz = pjz + o0 * c02 + o1 * c12 + o2 * c22 - piz;
        const float sq = vx * vx + vy * vy + vz * vz;
        const bool keep = (m > 0) & (sq >= RMIN2) & (sq <= RMAX2);
        acc += keep ? (1.0f / sq) : 0.0f;
    }

    // ---- reduce ----
    #pragma unroll
    for (int off = 32; off > 0; off >>= 1)
        acc += __shfl_down(acc, off, 64);

    if (lane == 0) wsum[wid] = acc;
    __syncthreads();
    if (t == 0) {
        float s = 0.0f;
        #pragma unroll
        for (int w = 0; w < NWAVES; ++w) s += wsum[w];
        atomicAdd(&out[b], 0.5f * s);
    }
}

extern "C" void kernel_launch(void* const* d_in, const int* in_sizes, int n_in,
                              void* d_out, int out_size, void* d_ws, size_t ws_size,
                              hipStream_t stream) {
    const float* positions = (const float*)d_in[0];
    const float* cell      = (const float*)d_in[1];
    const float* offsets   = (const float*)d_in[2];
    const int*   neighbors = (const int*)d_in[3];
    const int*   mask      = (const int*)d_in[4];
    float* out = (float*)d_out;

    (void)hipMemsetAsync(out, 0, out_size * sizeof(float), stream);

    repulsive_prior_kernel<<<GRID, THREADS, 0, stream>>>(
        positions, cell, offsets, neighbors, mask, out);
}